// Round 11
// baseline (440.636 us; speedup 1.0000x reference)
//
#include <hip/hip_runtime.h>

#define S 3072
#define D 512
#define H 8

constexpr float LN_EPS = 1e-6f;

typedef __attribute__((ext_vector_type(2))) _Float16 f16x2;
typedef __attribute__((ext_vector_type(8))) _Float16 f16x8;  // 8 f16 = 4 VGPRs
typedef __attribute__((ext_vector_type(4))) float f32x4;     // MFMA C/D frag

// v_cvt_pkrtz_f16_f32: pack 2 fp32 -> 2 fp16 (RTZ), bit_cast to our f16x2
__device__ __forceinline__ f16x2 cvt_pk(float lo, float hi) {
    return __builtin_bit_cast(f16x2, __builtin_amdgcn_cvt_pkrtz(lo, hi));
}

// -------------------- K1: QKV projection --------------------
// x[S,D] @ {Wq,Wk,Wv}[D,512] + b -> fp16 Q,K in [H][S][64] (Q pre-scaled by
// 1/16 = 1/sqrt(64)/2, folding entmax's /2 into the logits) and fp16 V^T in
// [H][64][S] with k-INTERLEAVED order within each 32-block: memory position
// j holds k = (j>>1) + 16*(j&1). This matches the PV A-fragment pair layout
// (see fused kernel) so MFMA k-slots line up. grid (S/8, 6), block 256.
__global__ void qkv_kernel(const float* __restrict__ x,
                           const float* __restrict__ Wq, const float* __restrict__ bq,
                           const float* __restrict__ Wk, const float* __restrict__ bk,
                           const float* __restrict__ Wv, const float* __restrict__ bv,
                           _Float16* __restrict__ Qb, _Float16* __restrict__ Kb,
                           _Float16* __restrict__ Vt) {
    const int rb = blockIdx.x;
    const int cb = blockIdx.y;
    const int t  = threadIdx.x;
    const int r0 = rb * 8;
    const int gc = cb * 256 + t;     // 0..1535
    const int m  = gc >> 9;          // 0:Q 1:K 2:V
    const int cc = gc & 511;
    const float* W    = (m == 0) ? Wq : (m == 1) ? Wk : Wv;
    const float* bias = (m == 0) ? bq : (m == 1) ? bk : bv;
    const float4* xf4 = (const float4*)(x + (size_t)r0 * D);

    float acc[8];
#pragma unroll
    for (int r = 0; r < 8; ++r) acc[r] = 0.f;

    for (int k4 = 0; k4 < D / 4; ++k4) {
        float w0 = W[(k4 * 4 + 0) * 512 + cc];
        float w1 = W[(k4 * 4 + 1) * 512 + cc];
        float w2 = W[(k4 * 4 + 2) * 512 + cc];
        float w3 = W[(k4 * 4 + 3) * 512 + cc];
#pragma unroll
        for (int r = 0; r < 8; ++r) {
            float4 xv = xf4[r * (D / 4) + k4];   // uniform -> s_load broadcast
            acc[r] += xv.x * w0 + xv.y * w1 + xv.z * w2 + xv.w * w3;
        }
    }
    const float b = bias[cc];
    const int h = cc >> 6, d = cc & 63;
    const float scale = (m == 0) ? 0.0625f : 1.0f;   // 1/sqrt(64) * 1/2 (w-space)
#pragma unroll
    for (int r = 0; r < 8; ++r) {
        float val = (acc[r] + b) * scale;
        if (m == 0)      Qb[(((size_t)h * S + (r0 + r)) << 6) + d] = (_Float16)val;
        else if (m == 1) Kb[(((size_t)h * S + (r0 + r)) << 6) + d] = (_Float16)val;
        else {
            int s  = r0 + r, bb = s & 31;
            int sp = (s & ~31) | (((bb & 15) << 1) | (bb >> 4));   // interleave
            Vt[((size_t)h * 64 + d) * S + sp] = (_Float16)val;
        }
    }
}

// -------------------- K2: fused logits + entmax-1.5 + PV --------------------
// 512 threads = 8 waves; block owns 16 q-rows x full S; wave w owns k-slice
// [w*384, w*384+384). Q pre-scaled so MFMA emits w = logit/2 directly.
// Pass A: 48 MFMA, keep w packed fp16 (zw, 48 VGPRs). Pass B: register-only
// Michelot iterations, 1 barrier/iter. Final pass: P pairs (k,k+16) ->
// plds[buf][pos][row] via ONE ds_write_b128/lane (double-buffered by jp
// parity -> no WAR chain), A-frag read 4x b32, attn written as 2x float4
// nontemporal from the row-sliced A-frag, PV MFMA with interleaved Vt.
__global__ __launch_bounds__(512, 2) void fused_attn_kernel(
        const _Float16* __restrict__ Qb, const _Float16* __restrict__ Kb,
        const _Float16* __restrict__ Vt, float* __restrict__ attn,
        float* __restrict__ AO) {
    __shared__ float sred[2][8][16][3];                 // ping-pong stats
    __shared__ __align__(16) f16x2 plds[2][8][16][16];  // [buf][w][pos][row]
    __shared__ float pacc[8][16][64];                   // per-wave PV partials
    const int bid = blockIdx.x;
    const int h = bid & 7, qt = bid >> 3;    // one head per XCD
    const int q0 = qt * 16;
    const int t = threadIdx.x;
    const int w = t >> 6, l = t & 63;
    const int lr = l & 15, lk = l >> 4;
    const int kbase = w * 384;

    const _Float16* Qh = Qb + ((size_t)h * S) * 64;
    const _Float16* Kh = Kb + ((size_t)h * S) * 64;
    const _Float16* Vh = Vt + (size_t)h * 64 * S;

    const f16x8 aq0 = *(const f16x8*)(Qh + (size_t)(q0 + lr) * 64 + lk * 8);
    const f16x8 aq1 = *(const f16x8*)(Qh + (size_t)(q0 + lr) * 64 + 32 + lk * 8);

    const f16x2 one2  = {(_Float16)1.f, (_Float16)1.f};
    const f16x2 zero2 = {(_Float16)0.f, (_Float16)0.f};
    const f16x2 big2  = {(_Float16)16384.f, (_Float16)16384.f};

    // ---- Pass A: logits once (already w-space); packed stats ----
    // zw[jp][r] = pair (w[row][k0+lr], w[row][k0+16+lr]), row = lk*4+r
    f16x2 zw[12][4];
    f16x2 m2[4];
    float s4[4] = {}, q4[4] = {};
#pragma unroll
    for (int r = 0; r < 4; ++r) m2[r] = (f16x2){(_Float16)-60000.f, (_Float16)-60000.f};
#pragma unroll
    for (int jp = 0; jp < 12; ++jp) {
        const _Float16* kp = Kh + (size_t)(kbase + jp * 32 + lr) * 64;
        f16x8 b00 = *(const f16x8*)(kp + lk * 8);
        f16x8 b01 = *(const f16x8*)(kp + 32 + lk * 8);
        f16x8 b10 = *(const f16x8*)(kp + 16 * 64 + lk * 8);
        f16x8 b11 = *(const f16x8*)(kp + 16 * 64 + 32 + lk * 8);
        f32x4 d0 = (f32x4){0.f, 0.f, 0.f, 0.f}, d1 = d0;
        d0 = __builtin_amdgcn_mfma_f32_16x16x32_f16(aq0, b00, d0, 0, 0, 0);
        d0 = __builtin_amdgcn_mfma_f32_16x16x32_f16(aq1, b01, d0, 0, 0, 0);
        d1 = __builtin_amdgcn_mfma_f32_16x16x32_f16(aq0, b10, d1, 0, 0, 0);
        d1 = __builtin_amdgcn_mfma_f32_16x16x32_f16(aq1, b11, d1, 0, 0, 0);
#pragma unroll
        for (int r = 0; r < 4; ++r) {
            f16x2 w2 = cvt_pk(d0[r], d1[r]);
            zw[jp][r] = w2;
            m2[r] = __builtin_elementwise_max(m2[r], w2);
            s4[r] = __builtin_amdgcn_fdot2(w2, one2, s4[r], false);
            q4[r] = __builtin_amdgcn_fdot2(w2, w2, q4[r], false);
        }
    }
    float m4[4];
#pragma unroll
    for (int r = 0; r < 4; ++r) m4[r] = fmaxf((float)m2[r][0], (float)m2[r][1]);
#pragma unroll
    for (int off = 1; off < 16; off <<= 1) {
#pragma unroll
        for (int r = 0; r < 4; ++r) {
            m4[r] = fmaxf(m4[r], __shfl_xor(m4[r], off, 64));
            s4[r] += __shfl_xor(s4[r], off, 64);
            q4[r] += __shfl_xor(q4[r], off, 64);
        }
    }
    if (lr == 0) {
#pragma unroll
        for (int r = 0; r < 4; ++r) {
            sred[0][w][lk * 4 + r][0] = m4[r];
            sred[0][w][lk * 4 + r][1] = s4[r];
            sred[0][w][lk * 4 + r][2] = q4[r];
        }
    }
    __syncthreads();

    // ---- closed-form full-support init (w-space) ----
    const float n = (float)S;
    float Tj;
    {
        float mj = -1e30f, sj = 0.f, qj = 0.f;
#pragma unroll
        for (int ww = 0; ww < 8; ++ww) {
            mj = fmaxf(mj, sred[0][ww][lr][0]);
            sj += sred[0][ww][lr][1];
            qj += sred[0][ww][lr][2];
        }
        float mean = sj * (1.f / n);
        float msq  = qj * (1.f / n);
        float ssv  = n * (msq - mean * mean);
        Tj = mean - sqrtf(fmaxf((1.f - ssv) / n, 0.f));
        Tj = fminf(fmaxf(Tj, mj - 1.0f), mj - 0.01f);
    }
    float T4[4];
#pragma unroll
    for (int r = 0; r < 4; ++r) T4[r] = __shfl(Tj, lk * 4 + r, 64);
    // no barrier: Pass B iter 0 writes sred[1], init read sred[0]

    // ---- Pass B: register-only packed Michelot iterations ----
    for (int it = 0; it < 8; ++it) {
        const int buf = (it + 1) & 1;
        f16x2 T2[4];
#pragma unroll
        for (int r = 0; r < 4; ++r) T2[r] = cvt_pk(T4[r], T4[r]);
        float f4[4] = {}, fp4[4] = {}, cn4[4] = {};
#pragma unroll
        for (int jp = 0; jp < 12; ++jp)
#pragma unroll
            for (int r = 0; r < 4; ++r) {
                f16x2 zc = __builtin_elementwise_max(zw[jp][r] - T2[r], zero2);
                f4[r]  = __builtin_amdgcn_fdot2(zc, zc, f4[r], false);
                fp4[r] = __builtin_amdgcn_fdot2(zc, one2, fp4[r], false);
                f16x2 g = __builtin_elementwise_min(zc * big2, one2);
                cn4[r] = __builtin_amdgcn_fdot2(g, one2, cn4[r], false);
            }
#pragma unroll
        for (int off = 1; off < 16; off <<= 1) {
#pragma unroll
            for (int r = 0; r < 4; ++r) {
                f4[r]  += __shfl_xor(f4[r],  off, 64);
                fp4[r] += __shfl_xor(fp4[r], off, 64);
                cn4[r] += __shfl_xor(cn4[r], off, 64);
            }
        }
        if (lr == 0) {
#pragma unroll
            for (int r = 0; r < 4; ++r) {
                sred[buf][w][lk * 4 + r][0] = f4[r];
                sred[buf][w][lk * 4 + r][1] = fp4[r];
                sred[buf][w][lk * 4 + r][2] = cn4[r];
            }
        }
        __syncthreads();
        float fj = 0.f, fpj = 0.f, cnj = 0.f;
#pragma unroll
        for (int ww = 0; ww < 8; ++ww) {
            fj  += sred[buf][ww][lr][0];
            fpj += sred[buf][ww][lr][1];
            cnj += sred[buf][ww][lr][2];
        }
        float ns   = fmaxf(cnj, 1.0f);
        float disc = fmaxf(fpj * fpj - ns * (fj - 1.0f), 0.f);
        float del  = (fpj - sqrtf(disc)) / ns;
#pragma unroll
        for (int r = 0; r < 4; ++r) T4[r] += __shfl(del, lk * 4 + r, 64);
        if (__all(fabsf(del) < 2e-6f)) break;   // block-uniform
    }

    // ---- Final: P pairs -> plds (dbuf) -> A-frag -> attn f4 stores + PV ----
    f16x2 T2[4];
#pragma unroll
    for (int r = 0; r < 4; ++r) T2[r] = cvt_pk(T4[r], T4[r]);
    f32x4 acc[4];
#pragma unroll
    for (int j = 0; j < 4; ++j) acc[j] = (f32x4){0.f, 0.f, 0.f, 0.f};
    float* arow = attn + ((size_t)h * S + q0) * S;
#pragma unroll
    for (int jp = 0; jp < 12; ++jp) {
        const int buf = jp & 1;
        // pack P pairs for rows lk*4+0..3 at pos lr; one b128 write
        union { f16x2 h2[4]; f16x8 v; } pw;
#pragma unroll
        for (int r = 0; r < 4; ++r) {
            f16x2 zc = __builtin_elementwise_max(zw[jp][r] - T2[r], zero2);
            pw.h2[r] = zc * zc;
        }
        *(f16x8*)&plds[buf][w][lr][lk * 4] = pw.v;
        // A-frag: row lr, pairs pos lk*4+0..3  (k = pos + 16*elem)
        union { f16x2 h2[4]; f16x8 v; } au;
#pragma unroll
        for (int u = 0; u < 4; ++u) au.h2[u] = plds[buf][w][lk * 4 + u][lr];
        f16x8 a = au.v;
        // attn stores: even elems = cols k0+lk*4..+3, odd = +16 (full rows)
        const size_t cb = (size_t)lr * S + kbase + jp * 32 + lk * 4;
        f32x4 lo = {(float)a[0], (float)a[2], (float)a[4], (float)a[6]};
        f32x4 hi = {(float)a[1], (float)a[3], (float)a[5], (float)a[7]};
        __builtin_nontemporal_store(lo, (f32x4*)&arow[cb]);
        __builtin_nontemporal_store(hi, (f32x4*)&arow[cb + 16]);
        // PV MFMA: B from interleaved Vt (same k-order as A pairs)
        const _Float16* vp = Vh + kbase + jp * 32 + lk * 8;
#pragma unroll
        for (int j = 0; j < 4; ++j) {
            f16x8 b = *(const f16x8*)(vp + (size_t)(j * 16 + lr) * S);
            acc[j] = __builtin_amdgcn_mfma_f32_16x16x32_f16(a, b, acc[j], 0, 0, 0);
        }
    }
    // cross-wave PV reduction
#pragma unroll
    for (int j = 0; j < 4; ++j)
#pragma unroll
        for (int r = 0; r < 4; ++r)
            pacc[w][lk * 4 + r][j * 16 + lr] = acc[j][r];
    __syncthreads();
    float* AOr = AO + ((size_t)h * S + q0) * 64;
#pragma unroll
    for (int u = 0; u < 2; ++u) {
        int idx = t + 512 * u;             // 0..1023
        int row = idx >> 6, col = idx & 63;
        float sum = 0.f;
#pragma unroll
        for (int ww = 0; ww < 8; ++ww) sum += pacc[ww][row][col];
        AOr[(size_t)row * 64 + col] = sum;
    }
}

// -------------------- K5: out-proj + residual + LayerNorm --------------------
// grid (S/4), block 256: 4 rows/block.
__global__ void outproj_ln_kernel(const float* __restrict__ AO, const float* __restrict__ Wo,
                                  const float* __restrict__ bo, const float* __restrict__ x,
                                  const float* __restrict__ gamma, const float* __restrict__ beta,
                                  float* __restrict__ out) {
    __shared__ float red[8];
    const int rb = blockIdx.x;
    const int t  = threadIdx.x;
    const int s0 = rb * 4;
    float acc0[4] = {}, acc1[4] = {};
    const int c0 = t, c1 = t + 256;
    const float4* A0 = (const float4*)AO;
    for (int k4 = 0; k4 < 128; ++k4) {
        int k = k4 * 4;
        int h = k >> 6, d4 = (k & 63) >> 2;
        float w00 = Wo[(k + 0) * 512 + c0], w10 = Wo[(k + 0) * 512 + c1];
        float w01 = Wo[(k + 1) * 512 + c0], w11 = Wo[(k + 1) * 512 + c1];
        float w02 = Wo[(k + 2) * 512 + c0], w12 = Wo[(k + 2) * 512 + c1];
        float w03 = Wo[(k + 3) * 512 + c0], w13 = Wo[(k + 3) * 512 + c1];
#pragma unroll
        for (int r = 0; r < 4; ++r) {
            float4 a = A0[((size_t)h * S + s0 + r) * 16 + d4];   // uniform
            acc0[r] += a.x * w00 + a.y * w01 + a.z * w02 + a.w * w03;
            acc1[r] += a.x * w10 + a.y * w11 + a.z * w12 + a.w * w13;
        }
    }
    const float b0 = bo[c0], b1 = bo[c1];
    const float g0 = gamma[c0], g1 = gamma[c1];
    const float be0 = beta[c0], be1 = beta[c1];
    const int wave = t >> 6, lane = t & 63;
    for (int r = 0; r < 4; ++r) {
        float y0 = acc0[r] + b0 + x[(size_t)(s0 + r) * 512 + c0];
        float y1 = acc1[r] + b1 + x[(size_t)(s0 + r) * 512 + c1];
        float s = y0 + y1, qq = y0 * y0 + y1 * y1;
#pragma unroll
        for (int off = 32; off; off >>= 1) {
            s  += __shfl_down(s, off, 64);
            qq += __shfl_down(qq, off, 64);
        }
        __syncthreads();
        if (lane == 0) { red[wave * 2] = s; red[wave * 2 + 1] = qq; }
        __syncthreads();
        s  = red[0] + red[2] + red[4] + red[6];
        qq = red[1] + red[3] + red[5] + red[7];
        float mu  = s * (1.0f / 512.0f);
        float var = qq * (1.0f / 512.0f) - mu * mu;
        float inv = rsqrtf(var + LN_EPS);
        out[(size_t)(s0 + r) * 512 + c0] = (y0 - mu) * inv * g0 + be0;
        out[(size_t)(s0 + r) * 512 + c1] = (y1 - mu) * inv * g1 + be1;
    }
}

extern "C" void kernel_launch(void* const* d_in, const int* in_sizes, int n_in,
                              void* d_out, int out_size, void* d_ws, size_t ws_size,
                              hipStream_t stream) {
    const float* x     = (const float*)d_in[0];
    const float* Wq    = (const float*)d_in[1];
    const float* bq    = (const float*)d_in[2];
    const float* Wk    = (const float*)d_in[3];
    const float* bk    = (const float*)d_in[4];
    const float* Wv    = (const float*)d_in[5];
    const float* bv    = (const float*)d_in[6];
    const float* Wo    = (const float*)d_in[7];
    const float* bo    = (const float*)d_in[8];
    const float* gamma = (const float*)d_in[9];
    const float* beta  = (const float*)d_in[10];

    float* out  = (float*)d_out;
    float* attn = out + (size_t)S * D;          // tuple output #2

    _Float16* Qb = (_Float16*)d_ws;             // [H][S][64] fp16, pre-scaled 1/16
    _Float16* Kb = Qb + (size_t)H * S * 64;     // [H][S][64] fp16
    _Float16* Vt = Kb + (size_t)H * S * 64;     // [H][64][S] fp16, k-interleaved
    float* AO = (float*)(Vt + (size_t)H * 64 * S);   // [H][S][64] f32

    qkv_kernel<<<dim3(S / 8, 6), 256, 0, stream>>>(x, Wq, bq, Wk, bk, Wv, bv, Qb, Kb, Vt);
    fused_attn_kernel<<<dim3((S / 16) * H), 512, 0, stream>>>(Qb, Kb, Vt, attn, AO);
    outproj_ln_kernel<<<dim3(S / 4), 256, 0, stream>>>(AO, Wo, bo, x, gamma, beta, out);
}

// Round 12
// 391.923 us; speedup vs baseline: 1.1243x; 1.1243x over previous
//
#include <hip/hip_runtime.h>

#define S 3072
#define D 512
#define H 8

constexpr float LN_EPS = 1e-6f;

typedef __attribute__((ext_vector_type(2))) _Float16 f16x2;
typedef __attribute__((ext_vector_type(8))) _Float16 f16x8;  // 8 f16 = 4 VGPRs
typedef __attribute__((ext_vector_type(4))) float f32x4;     // MFMA C/D frag

// v_cvt_pkrtz_f16_f32: pack 2 fp32 -> 2 fp16 (RTZ), bit_cast to our f16x2
__device__ __forceinline__ f16x2 cvt_pk(float lo, float hi) {
    return __builtin_bit_cast(f16x2, __builtin_amdgcn_cvt_pkrtz(lo, hi));
}

// -------------------- K1: QKV projection --------------------
// x[S,D] @ {Wq,Wk,Wv}[D,512] + b -> fp16 Q,K in [H][S][64] (Q pre-scaled by
// 1/16 = 1/sqrt(64)/2, folding entmax's /2 into the logits) and fp16 V^T in
// [H][64][S] with k-INTERLEAVED order within each 32-block: memory position
// j holds k = (j>>1) + 16*(j&1), matching the PV A-fragment pair layout.
__global__ void qkv_kernel(const float* __restrict__ x,
                           const float* __restrict__ Wq, const float* __restrict__ bq,
                           const float* __restrict__ Wk, const float* __restrict__ bk,
                           const float* __restrict__ Wv, const float* __restrict__ bv,
                           _Float16* __restrict__ Qb, _Float16* __restrict__ Kb,
                           _Float16* __restrict__ Vt) {
    const int rb = blockIdx.x;
    const int cb = blockIdx.y;
    const int t  = threadIdx.x;
    const int r0 = rb * 8;
    const int gc = cb * 256 + t;     // 0..1535
    const int m  = gc >> 9;          // 0:Q 1:K 2:V
    const int cc = gc & 511;
    const float* W    = (m == 0) ? Wq : (m == 1) ? Wk : Wv;
    const float* bias = (m == 0) ? bq : (m == 1) ? bk : bv;
    const float4* xf4 = (const float4*)(x + (size_t)r0 * D);

    float acc[8];
#pragma unroll
    for (int r = 0; r < 8; ++r) acc[r] = 0.f;

    for (int k4 = 0; k4 < D / 4; ++k4) {
        float w0 = W[(k4 * 4 + 0) * 512 + cc];
        float w1 = W[(k4 * 4 + 1) * 512 + cc];
        float w2 = W[(k4 * 4 + 2) * 512 + cc];
        float w3 = W[(k4 * 4 + 3) * 512 + cc];
#pragma unroll
        for (int r = 0; r < 8; ++r) {
            float4 xv = xf4[r * (D / 4) + k4];   // uniform -> s_load broadcast
            acc[r] += xv.x * w0 + xv.y * w1 + xv.z * w2 + xv.w * w3;
        }
    }
    const float b = bias[cc];
    const int h = cc >> 6, d = cc & 63;
    const float scale = (m == 0) ? 0.0625f : 1.0f;   // 1/sqrt(64) * 1/2 (w-space)
#pragma unroll
    for (int r = 0; r < 8; ++r) {
        float val = (acc[r] + b) * scale;
        if (m == 0)      Qb[(((size_t)h * S + (r0 + r)) << 6) + d] = (_Float16)val;
        else if (m == 1) Kb[(((size_t)h * S + (r0 + r)) << 6) + d] = (_Float16)val;
        else {
            int s  = r0 + r, bb = s & 31;
            int sp = (s & ~31) | (((bb & 15) << 1) | (bb >> 4));   // interleave
            Vt[((size_t)h * 64 + d) * S + sp] = (_Float16)val;
        }
    }
}

// -------------------- K2: fused logits + entmax-1.5 + PV --------------------
// 512 threads = 8 waves; block owns 16 q-rows x full S; wave w owns k-slice
// [w*384, w*384+384). Pass A: 48 MFMA -> w-space logits packed fp16 in zw
// (48 VGPRs) + per-row stats. Pass B: register-only Michelot, 1 barrier/iter.
// Phase T: per jp, P pairs -> plds (padded stride 20 f16x2, ~2-way banks,
// jp-parity double buffer) -> transposed A-frag OVERWRITES zw (azw) + attn
// f32x4 nontemporal stores (immediate offsets). Phase PV: per dv-quarter j,
// 4-reg accumulator, V loads via single pointer + immediate offsets; cross-
// wave reduce via LDS atomicAdd into 4 KB pacc. Total LDS 27.6 KB (was 52).
__global__ __launch_bounds__(512, 4) void fused_attn_kernel(
        const _Float16* __restrict__ Qb, const _Float16* __restrict__ Kb,
        const _Float16* __restrict__ Vt, float* __restrict__ attn,
        float* __restrict__ AO) {
    __shared__ float sred[2][8][16][3];                 // ping-pong stats (3 KB)
    __shared__ __align__(16) f16x2 plds[2][8][16][20];  // padded transpose (20.5 KB)
    __shared__ float pacc[16][64];                      // PV reduction (4 KB)
    const int bid = blockIdx.x;
    const int h = bid & 7, qt = bid >> 3;    // one head per XCD
    const int q0 = qt * 16;
    const int t = threadIdx.x;
    const int w = t >> 6, l = t & 63;
    const int lr = l & 15, lk = l >> 4;
    const int kbase = w * 384;

    // zero the PV accumulator (visibility guaranteed by Pass A's barrier)
    ((float*)pacc)[t] = 0.f;
    ((float*)pacc)[t + 512] = 0.f;

    const _Float16* Qh = Qb + ((size_t)h * S) * 64;
    const _Float16* Kh = Kb + ((size_t)h * S) * 64;
    const _Float16* Vh = Vt + (size_t)h * 64 * S;

    const f16x8 aq0 = *(const f16x8*)(Qh + (size_t)(q0 + lr) * 64 + lk * 8);
    const f16x8 aq1 = *(const f16x8*)(Qh + (size_t)(q0 + lr) * 64 + 32 + lk * 8);

    const f16x2 one2  = {(_Float16)1.f, (_Float16)1.f};
    const f16x2 zero2 = {(_Float16)0.f, (_Float16)0.f};
    const f16x2 big2  = {(_Float16)16384.f, (_Float16)16384.f};

    // ---- Pass A: logits once (already w-space); packed stats ----
    // zw[jp][r] = pair (w[row][k0+lr], w[row][k0+16+lr]), row = lk*4+r
    f16x2 zw[12][4];
    f16x2 m2[4];
    float s4[4] = {}, q4[4] = {};
#pragma unroll
    for (int r = 0; r < 4; ++r) m2[r] = (f16x2){(_Float16)-60000.f, (_Float16)-60000.f};
#pragma unroll
    for (int jp = 0; jp < 12; ++jp) {
        const _Float16* kp = Kh + (size_t)(kbase + jp * 32 + lr) * 64;
        f16x8 b00 = *(const f16x8*)(kp + lk * 8);
        f16x8 b01 = *(const f16x8*)(kp + 32 + lk * 8);
        f16x8 b10 = *(const f16x8*)(kp + 16 * 64 + lk * 8);
        f16x8 b11 = *(const f16x8*)(kp + 16 * 64 + 32 + lk * 8);
        f32x4 d0 = (f32x4){0.f, 0.f, 0.f, 0.f}, d1 = d0;
        d0 = __builtin_amdgcn_mfma_f32_16x16x32_f16(aq0, b00, d0, 0, 0, 0);
        d0 = __builtin_amdgcn_mfma_f32_16x16x32_f16(aq1, b01, d0, 0, 0, 0);
        d1 = __builtin_amdgcn_mfma_f32_16x16x32_f16(aq0, b10, d1, 0, 0, 0);
        d1 = __builtin_amdgcn_mfma_f32_16x16x32_f16(aq1, b11, d1, 0, 0, 0);
#pragma unroll
        for (int r = 0; r < 4; ++r) {
            f16x2 w2 = cvt_pk(d0[r], d1[r]);
            zw[jp][r] = w2;
            m2[r] = __builtin_elementwise_max(m2[r], w2);
            s4[r] = __builtin_amdgcn_fdot2(w2, one2, s4[r], false);
            q4[r] = __builtin_amdgcn_fdot2(w2, w2, q4[r], false);
        }
    }
    float m4[4];
#pragma unroll
    for (int r = 0; r < 4; ++r) m4[r] = fmaxf((float)m2[r][0], (float)m2[r][1]);
#pragma unroll
    for (int off = 1; off < 16; off <<= 1) {
#pragma unroll
        for (int r = 0; r < 4; ++r) {
            m4[r] = fmaxf(m4[r], __shfl_xor(m4[r], off, 64));
            s4[r] += __shfl_xor(s4[r], off, 64);
            q4[r] += __shfl_xor(q4[r], off, 64);
        }
    }
    if (lr == 0) {
#pragma unroll
        for (int r = 0; r < 4; ++r) {
            sred[0][w][lk * 4 + r][0] = m4[r];
            sred[0][w][lk * 4 + r][1] = s4[r];
            sred[0][w][lk * 4 + r][2] = q4[r];
        }
    }
    __syncthreads();

    // ---- closed-form full-support init (w-space) ----
    const float n = (float)S;
    float Tj;
    {
        float mj = -1e30f, sj = 0.f, qj = 0.f;
#pragma unroll
        for (int ww = 0; ww < 8; ++ww) {
            mj = fmaxf(mj, sred[0][ww][lr][0]);
            sj += sred[0][ww][lr][1];
            qj += sred[0][ww][lr][2];
        }
        float mean = sj * (1.f / n);
        float msq  = qj * (1.f / n);
        float ssv  = n * (msq - mean * mean);
        Tj = mean - sqrtf(fmaxf((1.f - ssv) / n, 0.f));
        Tj = fminf(fmaxf(Tj, mj - 1.0f), mj - 0.01f);
    }
    float T4[4];
#pragma unroll
    for (int r = 0; r < 4; ++r) T4[r] = __shfl(Tj, lk * 4 + r, 64);
    // no barrier: Pass B iter 0 writes sred[1], init read sred[0]

    // ---- Pass B: register-only packed Michelot iterations ----
    for (int it = 0; it < 8; ++it) {
        const int buf = (it + 1) & 1;
        f16x2 T2[4];
#pragma unroll
        for (int r = 0; r < 4; ++r) T2[r] = cvt_pk(T4[r], T4[r]);
        float f4[4] = {}, fp4[4] = {}, cn4[4] = {};
#pragma unroll
        for (int jp = 0; jp < 12; ++jp)
#pragma unroll
            for (int r = 0; r < 4; ++r) {
                f16x2 zc = __builtin_elementwise_max(zw[jp][r] - T2[r], zero2);
                f4[r]  = __builtin_amdgcn_fdot2(zc, zc, f4[r], false);
                fp4[r] = __builtin_amdgcn_fdot2(zc, one2, fp4[r], false);
                f16x2 g = __builtin_elementwise_min(zc * big2, one2);
                cn4[r] = __builtin_amdgcn_fdot2(g, one2, cn4[r], false);
            }
#pragma unroll
        for (int off = 1; off < 16; off <<= 1) {
#pragma unroll
            for (int r = 0; r < 4; ++r) {
                f4[r]  += __shfl_xor(f4[r],  off, 64);
                fp4[r] += __shfl_xor(fp4[r], off, 64);
                cn4[r] += __shfl_xor(cn4[r], off, 64);
            }
        }
        if (lr == 0) {
#pragma unroll
            for (int r = 0; r < 4; ++r) {
                sred[buf][w][lk * 4 + r][0] = f4[r];
                sred[buf][w][lk * 4 + r][1] = fp4[r];
                sred[buf][w][lk * 4 + r][2] = cn4[r];
            }
        }
        __syncthreads();
        float fj = 0.f, fpj = 0.f, cnj = 0.f;
#pragma unroll
        for (int ww = 0; ww < 8; ++ww) {
            fj  += sred[buf][ww][lr][0];
            fpj += sred[buf][ww][lr][1];
            cnj += sred[buf][ww][lr][2];
        }
        float ns   = fmaxf(cnj, 1.0f);
        float disc = fmaxf(fpj * fpj - ns * (fj - 1.0f), 0.f);
        float del  = (fpj - sqrtf(disc)) / ns;
#pragma unroll
        for (int r = 0; r < 4; ++r) T4[r] += __shfl(del, lk * 4 + r, 64);
        if (__all(fabsf(del) < 2e-6f)) break;   // block-uniform
    }

    // ---- Phase T: P -> plds -> transposed azw (in place) + attn stores ----
    f16x2 T2[4];
#pragma unroll
    for (int r = 0; r < 4; ++r) T2[r] = cvt_pk(T4[r], T4[r]);
    // base pointer for this lane's attn row-slice; all stores use imm offsets
    float* arow_t = attn + ((size_t)h * S + q0 + lr) * S + kbase + lk * 4;
    f16x8 azw[12];
#pragma unroll
    for (int jp = 0; jp < 12; ++jp) {
        const int buf = jp & 1;
        union { f16x2 h2[4]; f16x8 v; } pw;
#pragma unroll
        for (int r = 0; r < 4; ++r) {
            f16x2 zc = __builtin_elementwise_max(zw[jp][r] - T2[r], zero2);
            pw.h2[r] = zc * zc;
        }
        *(f16x8*)&plds[buf][w][lr][lk * 4] = pw.v;
        union { f16x2 h2[4]; f16x8 v; } au;
#pragma unroll
        for (int u = 0; u < 4; ++u) au.h2[u] = plds[buf][w][lk * 4 + u][lr];
        azw[jp] = au.v;
        f32x4 lo = {(float)au.v[0], (float)au.v[2], (float)au.v[4], (float)au.v[6]};
        f32x4 hi = {(float)au.v[1], (float)au.v[3], (float)au.v[5], (float)au.v[7]};
        __builtin_nontemporal_store(lo, (f32x4*)(arow_t + jp * 32));
        __builtin_nontemporal_store(hi, (f32x4*)(arow_t + jp * 32 + 16));
    }

    // ---- Phase PV: per dv-quarter, 4-reg acc, imm-offset V loads ----
#pragma unroll
    for (int j = 0; j < 4; ++j) {
        const _Float16* vpj = Vh + (size_t)(j * 16 + lr) * S + kbase + lk * 8;
        f32x4 a4 = (f32x4){0.f, 0.f, 0.f, 0.f};
#pragma unroll
        for (int jp = 0; jp < 12; ++jp) {
            f16x8 b = *(const f16x8*)(vpj + jp * 32);
            a4 = __builtin_amdgcn_mfma_f32_16x16x32_f16(azw[jp], b, a4, 0, 0, 0);
        }
#pragma unroll
        for (int r = 0; r < 4; ++r)
            atomicAdd(&pacc[lk * 4 + r][j * 16 + lr], a4[r]);
    }
    __syncthreads();
    float* AOr = AO + ((size_t)h * S + q0) * 64;
#pragma unroll
    for (int u = 0; u < 2; ++u) {
        int idx = t + 512 * u;             // 0..1023
        AOr[idx] = ((const float*)pacc)[idx];
    }
}

// -------------------- K5: out-proj + residual + LayerNorm --------------------
// grid (S/4), block 256: 4 rows/block.
__global__ void outproj_ln_kernel(const float* __restrict__ AO, const float* __restrict__ Wo,
                                  const float* __restrict__ bo, const float* __restrict__ x,
                                  const float* __restrict__ gamma, const float* __restrict__ beta,
                                  float* __restrict__ out) {
    __shared__ float red[8];
    const int rb = blockIdx.x;
    const int t  = threadIdx.x;
    const int s0 = rb * 4;
    float acc0[4] = {}, acc1[4] = {};
    const int c0 = t, c1 = t + 256;
    const float4* A0 = (const float4*)AO;
    for (int k4 = 0; k4 < 128; ++k4) {
        int k = k4 * 4;
        int h = k >> 6, d4 = (k & 63) >> 2;
        float w00 = Wo[(k + 0) * 512 + c0], w10 = Wo[(k + 0) * 512 + c1];
        float w01 = Wo[(k + 1) * 512 + c0], w11 = Wo[(k + 1) * 512 + c1];
        float w02 = Wo[(k + 2) * 512 + c0], w12 = Wo[(k + 2) * 512 + c1];
        float w03 = Wo[(k + 3) * 512 + c0], w13 = Wo[(k + 3) * 512 + c1];
#pragma unroll
        for (int r = 0; r < 4; ++r) {
            float4 a = A0[((size_t)h * S + s0 + r) * 16 + d4];   // uniform
            acc0[r] += a.x * w00 + a.y * w01 + a.z * w02 + a.w * w03;
            acc1[r] += a.x * w10 + a.y * w11 + a.z * w12 + a.w * w13;
        }
    }
    const float b0 = bo[c0], b1 = bo[c1];
    const float g0 = gamma[c0], g1 = gamma[c1];
    const float be0 = beta[c0], be1 = beta[c1];
    const int wave = t >> 6, lane = t & 63;
    for (int r = 0; r < 4; ++r) {
        float y0 = acc0[r] + b0 + x[(size_t)(s0 + r) * 512 + c0];
        float y1 = acc1[r] + b1 + x[(size_t)(s0 + r) * 512 + c1];
        float s = y0 + y1, qq = y0 * y0 + y1 * y1;
#pragma unroll
        for (int off = 32; off; off >>= 1) {
            s  += __shfl_down(s, off, 64);
            qq += __shfl_down(qq, off, 64);
        }
        __syncthreads();
        if (lane == 0) { red[wave * 2] = s; red[wave * 2 + 1] = qq; }
        __syncthreads();
        s  = red[0] + red[2] + red[4] + red[6];
        qq = red[1] + red[3] + red[5] + red[7];
        float mu  = s * (1.0f / 512.0f);
        float var = qq * (1.0f / 512.0f) - mu * mu;
        float inv = rsqrtf(var + LN_EPS);
        out[(size_t)(s0 + r) * 512 + c0] = (y0 - mu) * inv * g0 + be0;
        out[(size_t)(s0 + r) * 512 + c1] = (y1 - mu) * inv * g1 + be1;
    }
}

extern "C" void kernel_launch(void* const* d_in, const int* in_sizes, int n_in,
                              void* d_out, int out_size, void* d_ws, size_t ws_size,
                              hipStream_t stream) {
    const float* x     = (const float*)d_in[0];
    const float* Wq    = (const float*)d_in[1];
    const float* bq    = (const float*)d_in[2];
    const float* Wk    = (const float*)d_in[3];
    const float* bk    = (const float*)d_in[4];
    const float* Wv    = (const float*)d_in[5];
    const float* bv    = (const float*)d_in[6];
    const float* Wo    = (const float*)d_in[7];
    const float* bo    = (const float*)d_in[8];
    const float* gamma = (const float*)d_in[9];
    const float* beta  = (const float*)d_in[10];

    float* out  = (float*)d_out;
    float* attn = out + (size_t)S * D;          // tuple output #2

    _Float16* Qb = (_Float16*)d_ws;             // [H][S][64] fp16, pre-scaled 1/16
    _Float16* Kb = Qb + (size_t)H * S * 64;     // [H][S][64] fp16
    _Float16* Vt = Kb + (size_t)H * S * 64;     // [H][64][S] fp16, k-interleaved
    float* AO = (float*)(Vt + (size_t)H * 64 * S);   // [H][S][64] f32

    qkv_kernel<<<dim3(S / 8, 6), 256, 0, stream>>>(x, Wq, bq, Wk, bk, Wv, bv, Qb, Kb, Vt);
    fused_attn_kernel<<<dim3((S / 16) * H), 512, 0, stream>>>(Qb, Kb, Vt, attn, AO);
    outproj_ln_kernel<<<dim3(S / 4), 256, 0, stream>>>(AO, Wo, bo, x, gamma, beta, out);
}

// Round 13
// 386.906 us; speedup vs baseline: 1.1389x; 1.0130x over previous
//
#include <hip/hip_runtime.h>

#define S 3072
#define D 512
#define H 8

constexpr float LN_EPS = 1e-6f;

typedef __attribute__((ext_vector_type(2))) _Float16 f16x2;
typedef __attribute__((ext_vector_type(8))) _Float16 f16x8;  // 8 f16 = 4 VGPRs
typedef __attribute__((ext_vector_type(4))) float f32x4;     // MFMA C/D frag

// v_cvt_pkrtz_f16_f32: pack 2 fp32 -> 2 fp16 (RTZ), bit_cast to our f16x2
__device__ __forceinline__ f16x2 cvt_pk(float lo, float hi) {
    return __builtin_bit_cast(f16x2, __builtin_amdgcn_cvt_pkrtz(lo, hi));
}

// -------------------- P0a: W transpose + fp16 convert --------------------
// WtAll[(mat*512 + c)*512 + k] = W_mat[k][c], mats: 0=Wq 1=Wk 2=Wv 3=Wo.
// grid (2, 8, 4), 256 thr. Reads coalesced (c across lanes), writes 16B/lane.
__global__ void prep_w_kernel(const float* __restrict__ Wq, const float* __restrict__ Wk,
                              const float* __restrict__ Wv, const float* __restrict__ Wo,
                              _Float16* __restrict__ WtAll) {
    const int c  = blockIdx.x * 256 + threadIdx.x;   // 0..511
    const int k0 = blockIdx.y * 64;
    const int mat = blockIdx.z;
    const float* W = (mat == 0) ? Wq : (mat == 1) ? Wk : (mat == 2) ? Wv : Wo;
    _Float16* dst = WtAll + ((size_t)(mat * 512 + c)) * 512 + k0;
#pragma unroll
    for (int kb = 0; kb < 8; ++kb) {
        f16x8 v;
#pragma unroll
        for (int i = 0; i < 8; ++i)
            v[i] = (_Float16)W[(size_t)(k0 + kb * 8 + i) * 512 + c];
        *(f16x8*)(dst + kb * 8) = v;
    }
}

// -------------------- P0b: x -> fp16 --------------------
__global__ void prep_x_kernel(const float* __restrict__ x, _Float16* __restrict__ xh) {
    const int i = blockIdx.x * 256 + threadIdx.x;    // S*D/8 = 196608 threads
    const float4* xf = (const float4*)x;
    float4 a = xf[i * 2], b = xf[i * 2 + 1];
    f16x8 v = {(_Float16)a.x, (_Float16)a.y, (_Float16)a.z, (_Float16)a.w,
               (_Float16)b.x, (_Float16)b.y, (_Float16)b.z, (_Float16)b.w};
    *(f16x8*)(xh + (size_t)i * 8) = v;
}

// -------------------- K1: QKV projection (MFMA) --------------------
// C[3072,1536] = xh @ WtAll^T(cols 0..1535). grid (48, 24), 256 thr = 4 waves;
// block tile 64 rows x 64 cols, wave = 16 rows. Epilogue: Q scaled 1/16
// (w-space fold), K plain, V -> V^T [H][64][S] k-interleaved (pos j holds
// k = (j>>1)+16*(j&1) within each 32-block).
__global__ __launch_bounds__(256) void qkv_mfma_kernel(
        const _Float16* __restrict__ xh, const _Float16* __restrict__ WtAll,
        const float* __restrict__ bq, const float* __restrict__ bk,
        const float* __restrict__ bv,
        _Float16* __restrict__ Qb, _Float16* __restrict__ Kb,
        _Float16* __restrict__ Vt) {
    const int t = threadIdx.x;
    const int w = t >> 6, l = t & 63, lr = l & 15, lk = l >> 4;
    const int r0 = blockIdx.x * 64 + w * 16;
    const int c0 = blockIdx.y * 64;
    const _Float16* Ar = xh + (size_t)(r0 + lr) * 512 + lk * 8;
    const _Float16* Br = WtAll + (size_t)(c0 + lr) * 512 + lk * 8;

    f32x4 acc[4];
#pragma unroll
    for (int j = 0; j < 4; ++j) acc[j] = (f32x4){0.f, 0.f, 0.f, 0.f};
    for (int ks = 0; ks < 16; ++ks) {
        f16x8 a = *(const f16x8*)(Ar + ks * 32);
#pragma unroll
        for (int j = 0; j < 4; ++j) {
            f16x8 b = *(const f16x8*)(Br + (size_t)(j * 16) * 512 + ks * 32);
            acc[j] = __builtin_amdgcn_mfma_f32_16x16x32_f16(a, b, acc[j], 0, 0, 0);
        }
    }
    const int m = c0 >> 9;                   // block-uniform: 0=Q 1=K 2=V
    const float* bias = (m == 0) ? bq : (m == 1) ? bk : bv;
#pragma unroll
    for (int j = 0; j < 4; ++j) {
        const int cc = (c0 & 511) + j * 16 + lr;
        const int h = cc >> 6, d = cc & 63;
        const float bb_ = bias[cc];
#pragma unroll
        for (int r = 0; r < 4; ++r) {
            const int row = r0 + lk * 4 + r;
            float val = acc[j][r] + bb_;
            if (m == 0)      Qb[((size_t)h * S + row) * 64 + d] = (_Float16)(val * 0.0625f);
            else if (m == 1) Kb[((size_t)h * S + row) * 64 + d] = (_Float16)val;
            else {
                int bb = row & 31;
                int sp = (row & ~31) | (((bb & 15) << 1) | (bb >> 4));
                Vt[((size_t)h * 64 + d) * S + sp] = (_Float16)val;
            }
        }
    }
}

// -------------------- K2: fused logits + entmax-1.5 + PV --------------------
// 512 threads = 8 waves; block owns 16 q-rows x full S; wave w owns k-slice
// [w*384, w*384+384). Pass A: 48 MFMA -> w-space logits packed fp16 in U.p
// (48 VGPRs) + stats. Pass B: register-only Michelot, 1 barrier/iter.
// Phase T: transpose via plds, result OVERLAYS U (union -> no zw+azw double
// liveness, round-12 spill fix) + attn f32x4 nontemporal stores. Phase PV:
// per dv-quarter, 4-reg acc, imm-offset V loads, LDS atomicAdd reduce.
// launch_bounds(512,3): ~85-VGPR cap, 3 blocks/CU.
__global__ __launch_bounds__(512, 3) void fused_attn_kernel(
        const _Float16* __restrict__ Qb, const _Float16* __restrict__ Kb,
        const _Float16* __restrict__ Vt, float* __restrict__ attn,
        _Float16* __restrict__ AOh) {
    __shared__ float sred[2][8][16][3];                 // ping-pong stats (3 KB)
    __shared__ __align__(16) f16x2 plds[2][8][16][20];  // padded transpose (20.5 KB)
    __shared__ float pacc[16][64];                      // PV reduction (4 KB)
    const int bid = blockIdx.x;
    const int h = bid & 7, qt = bid >> 3;    // one head per XCD
    const int q0 = qt * 16;
    const int t = threadIdx.x;
    const int w = t >> 6, l = t & 63;
    const int lr = l & 15, lk = l >> 4;
    const int kbase = w * 384;

    ((float*)pacc)[t] = 0.f;
    ((float*)pacc)[t + 512] = 0.f;

    const _Float16* Qh = Qb + ((size_t)h * S) * 64;
    const _Float16* Kh = Kb + ((size_t)h * S) * 64;
    const _Float16* Vh = Vt + (size_t)h * 64 * S;

    const f16x8 aq0 = *(const f16x8*)(Qh + (size_t)(q0 + lr) * 64 + lk * 8);
    const f16x8 aq1 = *(const f16x8*)(Qh + (size_t)(q0 + lr) * 64 + 32 + lk * 8);

    const f16x2 one2  = {(_Float16)1.f, (_Float16)1.f};
    const f16x2 zero2 = {(_Float16)0.f, (_Float16)0.f};
    const f16x2 big2  = {(_Float16)16384.f, (_Float16)16384.f};

    // U.p = w-space logit pairs (Pass A/B); U.a = transposed A-frags (PV)
    union ZU { f16x2 p[12][4]; f16x8 a[12]; } U;

    // ---- Pass A: logits once; packed stats ----
    f16x2 m2[4];
    float s4[4] = {}, q4[4] = {};
#pragma unroll
    for (int r = 0; r < 4; ++r) m2[r] = (f16x2){(_Float16)-60000.f, (_Float16)-60000.f};
#pragma unroll
    for (int jp = 0; jp < 12; ++jp) {
        const _Float16* kp = Kh + (size_t)(kbase + jp * 32 + lr) * 64;
        f16x8 b00 = *(const f16x8*)(kp + lk * 8);
        f16x8 b01 = *(const f16x8*)(kp + 32 + lk * 8);
        f16x8 b10 = *(const f16x8*)(kp + 16 * 64 + lk * 8);
        f16x8 b11 = *(const f16x8*)(kp + 16 * 64 + 32 + lk * 8);
        f32x4 d0 = (f32x4){0.f, 0.f, 0.f, 0.f}, d1 = d0;
        d0 = __builtin_amdgcn_mfma_f32_16x16x32_f16(aq0, b00, d0, 0, 0, 0);
        d0 = __builtin_amdgcn_mfma_f32_16x16x32_f16(aq1, b01, d0, 0, 0, 0);
        d1 = __builtin_amdgcn_mfma_f32_16x16x32_f16(aq0, b10, d1, 0, 0, 0);
        d1 = __builtin_amdgcn_mfma_f32_16x16x32_f16(aq1, b11, d1, 0, 0, 0);
#pragma unroll
        for (int r = 0; r < 4; ++r) {
            f16x2 w2 = cvt_pk(d0[r], d1[r]);
            U.p[jp][r] = w2;
            m2[r] = __builtin_elementwise_max(m2[r], w2);
            s4[r] = __builtin_amdgcn_fdot2(w2, one2, s4[r], false);
            q4[r] = __builtin_amdgcn_fdot2(w2, w2, q4[r], false);
        }
    }
    float m4[4];
#pragma unroll
    for (int r = 0; r < 4; ++r) m4[r] = fmaxf((float)m2[r][0], (float)m2[r][1]);
#pragma unroll
    for (int off = 1; off < 16; off <<= 1) {
#pragma unroll
        for (int r = 0; r < 4; ++r) {
            m4[r] = fmaxf(m4[r], __shfl_xor(m4[r], off, 64));
            s4[r] += __shfl_xor(s4[r], off, 64);
            q4[r] += __shfl_xor(q4[r], off, 64);
        }
    }
    if (lr == 0) {
#pragma unroll
        for (int r = 0; r < 4; ++r) {
            sred[0][w][lk * 4 + r][0] = m4[r];
            sred[0][w][lk * 4 + r][1] = s4[r];
            sred[0][w][lk * 4 + r][2] = q4[r];
        }
    }
    __syncthreads();

    // ---- closed-form full-support init (w-space) ----
    const float n = (float)S;
    float Tj;
    {
        float mj = -1e30f, sj = 0.f, qj = 0.f;
#pragma unroll
        for (int ww = 0; ww < 8; ++ww) {
            mj = fmaxf(mj, sred[0][ww][lr][0]);
            sj += sred[0][ww][lr][1];
            qj += sred[0][ww][lr][2];
        }
        float mean = sj * (1.f / n);
        float msq  = qj * (1.f / n);
        float ssv  = n * (msq - mean * mean);
        Tj = mean - sqrtf(fmaxf((1.f - ssv) / n, 0.f));
        Tj = fminf(fmaxf(Tj, mj - 1.0f), mj - 0.01f);
    }
    float T4[4];
#pragma unroll
    for (int r = 0; r < 4; ++r) T4[r] = __shfl(Tj, lk * 4 + r, 64);

    // ---- Pass B: register-only packed Michelot iterations ----
    for (int it = 0; it < 8; ++it) {
        const int buf = (it + 1) & 1;
        f16x2 T2[4];
#pragma unroll
        for (int r = 0; r < 4; ++r) T2[r] = cvt_pk(T4[r], T4[r]);
        float f4[4] = {}, fp4[4] = {}, cn4[4] = {};
#pragma unroll
        for (int jp = 0; jp < 12; ++jp)
#pragma unroll
            for (int r = 0; r < 4; ++r) {
                f16x2 zc = __builtin_elementwise_max(U.p[jp][r] - T2[r], zero2);
                f4[r]  = __builtin_amdgcn_fdot2(zc, zc, f4[r], false);
                fp4[r] = __builtin_amdgcn_fdot2(zc, one2, fp4[r], false);
                f16x2 g = __builtin_elementwise_min(zc * big2, one2);
                cn4[r] = __builtin_amdgcn_fdot2(g, one2, cn4[r], false);
            }
#pragma unroll
        for (int off = 1; off < 16; off <<= 1) {
#pragma unroll
            for (int r = 0; r < 4; ++r) {
                f4[r]  += __shfl_xor(f4[r],  off, 64);
                fp4[r] += __shfl_xor(fp4[r], off, 64);
                cn4[r] += __shfl_xor(cn4[r], off, 64);
            }
        }
        if (lr == 0) {
#pragma unroll
            for (int r = 0; r < 4; ++r) {
                sred[buf][w][lk * 4 + r][0] = f4[r];
                sred[buf][w][lk * 4 + r][1] = fp4[r];
                sred[buf][w][lk * 4 + r][2] = cn4[r];
            }
        }
        __syncthreads();
        float fj = 0.f, fpj = 0.f, cnj = 0.f;
#pragma unroll
        for (int ww = 0; ww < 8; ++ww) {
            fj  += sred[buf][ww][lr][0];
            fpj += sred[buf][ww][lr][1];
            cnj += sred[buf][ww][lr][2];
        }
        float ns   = fmaxf(cnj, 1.0f);
        float disc = fmaxf(fpj * fpj - ns * (fj - 1.0f), 0.f);
        float del  = (fpj - sqrtf(disc)) / ns;
#pragma unroll
        for (int r = 0; r < 4; ++r) T4[r] += __shfl(del, lk * 4 + r, 64);
        if (__all(fabsf(del) < 2e-6f)) break;   // block-uniform
    }

    // ---- Phase T: P -> plds -> transposed frags overlay U + attn stores ----
    f16x2 T2[4];
#pragma unroll
    for (int r = 0; r < 4; ++r) T2[r] = cvt_pk(T4[r], T4[r]);
    float* arow_t = attn + ((size_t)h * S + q0 + lr) * S + kbase + lk * 4;
#pragma unroll
    for (int jp = 0; jp < 12; ++jp) {
        const int buf = jp & 1;
        union { f16x2 h2[4]; f16x8 v; } pw;
#pragma unroll
        for (int r = 0; r < 4; ++r) {
            f16x2 zc = __builtin_elementwise_max(U.p[jp][r] - T2[r], zero2);
            pw.h2[r] = zc * zc;
        }
        *(f16x8*)&plds[buf][w][lr][lk * 4] = pw.v;
        union { f16x2 h2[4]; f16x8 v; } au;
#pragma unroll
        for (int u = 0; u < 4; ++u) au.h2[u] = plds[buf][w][lk * 4 + u][lr];
        U.a[jp] = au.v;                    // overlays p[jp] after its last use
        f32x4 lo = {(float)au.v[0], (float)au.v[2], (float)au.v[4], (float)au.v[6]};
        f32x4 hi = {(float)au.v[1], (float)au.v[3], (float)au.v[5], (float)au.v[7]};
        __builtin_nontemporal_store(lo, (f32x4*)(arow_t + jp * 32));
        __builtin_nontemporal_store(hi, (f32x4*)(arow_t + jp * 32 + 16));
    }

    // ---- Phase PV: per dv-quarter, 4-reg acc, imm-offset V loads ----
#pragma unroll
    for (int j = 0; j < 4; ++j) {
        const _Float16* vpj = Vh + (size_t)(j * 16 + lr) * S + kbase + lk * 8;
        f32x4 a4 = (f32x4){0.f, 0.f, 0.f, 0.f};
#pragma unroll
        for (int jp = 0; jp < 12; ++jp) {
            f16x8 b = *(const f16x8*)(vpj + jp * 32);
            a4 = __builtin_amdgcn_mfma_f32_16x16x32_f16(U.a[jp], b, a4, 0, 0, 0);
        }
#pragma unroll
        for (int r = 0; r < 4; ++r)
            atomicAdd(&pacc[lk * 4 + r][j * 16 + lr], a4[r]);
    }
    __syncthreads();
    _Float16* AOr = AOh + (size_t)q0 * 512 + h * 64;
#pragma unroll
    for (int u = 0; u < 2; ++u) {
        int idx = t + 512 * u;             // 0..1023
        int row = idx >> 6, col = idx & 63;
        AOr[(size_t)row * 512 + col] = (_Float16)pacc[row][col];
    }
}

// -------------------- K5: out-proj + residual + LayerNorm (MFMA) --------------------
// grid (192), 256 thr = 4 waves; block = 16 rows x 512 cols (wave w: cols
// w*128..+127), K=512. LN: D-frag row partials -> shfl over 16 col-lanes ->
// 4-wave LDS combine -> normalize + store fp32.
__global__ __launch_bounds__(256) void outproj_mfma_kernel(
        const _Float16* __restrict__ AOh, const _Float16* __restrict__ WtAll,
        const float* __restrict__ bo, const float* __restrict__ x,
        const float* __restrict__ gamma, const float* __restrict__ beta,
        float* __restrict__ out) {
    __shared__ float red[4][16][2];
    const int s0 = blockIdx.x * 16;
    const int t = threadIdx.x, w = t >> 6, l = t & 63;
    const int lr = l & 15, lk = l >> 4;
    const _Float16* Ar = AOh + (size_t)(s0 + lr) * 512 + lk * 8;
    const _Float16* Br = WtAll + (size_t)(1536 + w * 128 + lr) * 512 + lk * 8;

    f32x4 acc[8];
#pragma unroll
    for (int j = 0; j < 8; ++j) acc[j] = (f32x4){0.f, 0.f, 0.f, 0.f};
    for (int ks = 0; ks < 16; ++ks) {
        f16x8 a = *(const f16x8*)(Ar + ks * 32);
#pragma unroll
        for (int j = 0; j < 8; ++j) {
            f16x8 b = *(const f16x8*)(Br + (size_t)(j * 16) * 512 + ks * 32);
            acc[j] = __builtin_amdgcn_mfma_f32_16x16x32_f16(a, b, acc[j], 0, 0, 0);
        }
    }
    float s_[4] = {}, q_[4] = {};
#pragma unroll
    for (int j = 0; j < 8; ++j) {
        const int col = w * 128 + j * 16 + lr;
        const float b0 = bo[col];
#pragma unroll
        for (int r = 0; r < 4; ++r) {
            float y = acc[j][r] + b0 + x[(size_t)(s0 + lk * 4 + r) * 512 + col];
            acc[j][r] = y;                   // keep y in the acc regs
            s_[r] += y;
            q_[r] = fmaf(y, y, q_[r]);
        }
    }
#pragma unroll
    for (int off = 1; off < 16; off <<= 1) {
#pragma unroll
        for (int r = 0; r < 4; ++r) {
            s_[r] += __shfl_xor(s_[r], off, 64);
            q_[r] += __shfl_xor(q_[r], off, 64);
        }
    }
    if (lr == 0) {
#pragma unroll
        for (int r = 0; r < 4; ++r) {
            red[w][lk * 4 + r][0] = s_[r];
            red[w][lk * 4 + r][1] = q_[r];
        }
    }
    __syncthreads();
#pragma unroll
    for (int r = 0; r < 4; ++r) {
        const int rowi = lk * 4 + r;
        float sj = red[0][rowi][0] + red[1][rowi][0] + red[2][rowi][0] + red[3][rowi][0];
        float qj = red[0][rowi][1] + red[1][rowi][1] + red[2][rowi][1] + red[3][rowi][1];
        float mu  = sj * (1.0f / 512.0f);
        float var = qj * (1.0f / 512.0f) - mu * mu;
        float inv = rsqrtf(var + LN_EPS);
        const size_t rbase = (size_t)(s0 + rowi) * 512;
#pragma unroll
        for (int j = 0; j < 8; ++j) {
            const int col = w * 128 + j * 16 + lr;
            out[rbase + col] = (acc[j][r] - mu) * inv * gamma[col] + beta[col];
        }
    }
}

extern "C" void kernel_launch(void* const* d_in, const int* in_sizes, int n_in,
                              void* d_out, int out_size, void* d_ws, size_t ws_size,
                              hipStream_t stream) {
    const float* x     = (const float*)d_in[0];
    const float* Wq    = (const float*)d_in[1];
    const float* bq    = (const float*)d_in[2];
    const float* Wk    = (const float*)d_in[3];
    const float* bk    = (const float*)d_in[4];
    const float* Wv    = (const float*)d_in[5];
    const float* bv    = (const float*)d_in[6];
    const float* Wo    = (const float*)d_in[7];
    const float* bo    = (const float*)d_in[8];
    const float* gamma = (const float*)d_in[9];
    const float* beta  = (const float*)d_in[10];

    float* out  = (float*)d_out;
    float* attn = out + (size_t)S * D;          // tuple output #2

    _Float16* Qb    = (_Float16*)d_ws;          // [H][S][64] fp16, pre-scaled 1/16
    _Float16* Kb    = Qb + (size_t)H * S * 64;  // [H][S][64] fp16
    _Float16* Vt    = Kb + (size_t)H * S * 64;  // [H][64][S] fp16, k-interleaved
    _Float16* xh    = Vt + (size_t)H * S * 64;  // [S][512] fp16
    _Float16* WtAll = xh + (size_t)S * 512;     // [2048][512] fp16 (Q,K,V,O transposed)
    _Float16* AOh   = WtAll + (size_t)2048 * 512; // [S][512] fp16

    prep_w_kernel<<<dim3(2, 8, 4), 256, 0, stream>>>(Wq, Wk, Wv, Wo, WtAll);
    prep_x_kernel<<<dim3(S * D / 2048), 256, 0, stream>>>(x, xh);
    qkv_mfma_kernel<<<dim3(48, 24), 256, 0, stream>>>(xh, WtAll, bq, bk, bv, Qb, Kb, Vt);
    fused_attn_kernel<<<dim3((S / 16) * H), 512, 0, stream>>>(Qb, Kb, Vt, attn, AOh);
    outproj_mfma_kernel<<<dim3(S / 16), 256, 0, stream>>>(AOh, WtAll, bo, x, gamma, beta, out);
}

// Round 14
// 386.347 us; speedup vs baseline: 1.1405x; 1.0014x over previous
//
#include <hip/hip_runtime.h>

#define S 3072
#define D 512
#define H 8

constexpr float LN_EPS = 1e-6f;

typedef __attribute__((ext_vector_type(2))) _Float16 f16x2;
typedef __attribute__((ext_vector_type(8))) _Float16 f16x8;  // 8 f16 = 4 VGPRs
typedef __attribute__((ext_vector_type(4))) float f32x4;     // MFMA C/D frag

// v_cvt_pkrtz_f16_f32: pack 2 fp32 -> 2 fp16 (RTZ), bit_cast to our f16x2
__device__ __forceinline__ f16x2 cvt_pk(float lo, float hi) {
    return __builtin_bit_cast(f16x2, __builtin_amdgcn_cvt_pkrtz(lo, hi));
}

// -------------------- P0a: W transpose + fp16 convert --------------------
// WtAll[(mat*512 + c)*512 + k] = W_mat[k][c], mats: 0=Wq 1=Wk 2=Wv 3=Wo.
__global__ void prep_w_kernel(const float* __restrict__ Wq, const float* __restrict__ Wk,
                              const float* __restrict__ Wv, const float* __restrict__ Wo,
                              _Float16* __restrict__ WtAll) {
    const int c  = blockIdx.x * 256 + threadIdx.x;   // 0..511
    const int k0 = blockIdx.y * 64;
    const int mat = blockIdx.z;
    const float* W = (mat == 0) ? Wq : (mat == 1) ? Wk : (mat == 2) ? Wv : Wo;
    _Float16* dst = WtAll + ((size_t)(mat * 512 + c)) * 512 + k0;
#pragma unroll
    for (int kb = 0; kb < 8; ++kb) {
        f16x8 v;
#pragma unroll
        for (int i = 0; i < 8; ++i)
            v[i] = (_Float16)W[(size_t)(k0 + kb * 8 + i) * 512 + c];
        *(f16x8*)(dst + kb * 8) = v;
    }
}

// -------------------- P0b: x -> fp16 --------------------
__global__ void prep_x_kernel(const float* __restrict__ x, _Float16* __restrict__ xh) {
    const int i = blockIdx.x * 256 + threadIdx.x;    // S*D/8 threads
    const float4* xf = (const float4*)x;
    float4 a = xf[i * 2], b = xf[i * 2 + 1];
    f16x8 v = {(_Float16)a.x, (_Float16)a.y, (_Float16)a.z, (_Float16)a.w,
               (_Float16)b.x, (_Float16)b.y, (_Float16)b.z, (_Float16)b.w};
    *(f16x8*)(xh + (size_t)i * 8) = v;
}

// -------------------- K1: QKV projection (MFMA) --------------------
// C[3072,1536] = xh @ WtAll^T(cols 0..1535). grid (48, 24), 256 thr = 4 waves.
// Epilogue: Q scaled 1/16 (w-space fold), K plain, V -> V^T [H][64][S]
// k-interleaved (pos j holds k = (j>>1)+16*(j&1) within each 32-block).
__global__ __launch_bounds__(256) void qkv_mfma_kernel(
        const _Float16* __restrict__ xh, const _Float16* __restrict__ WtAll,
        const float* __restrict__ bq, const float* __restrict__ bk,
        const float* __restrict__ bv,
        _Float16* __restrict__ Qb, _Float16* __restrict__ Kb,
        _Float16* __restrict__ Vt) {
    const int t = threadIdx.x;
    const int w = t >> 6, l = t & 63, lr = l & 15, lk = l >> 4;
    const int r0 = blockIdx.x * 64 + w * 16;
    const int c0 = blockIdx.y * 64;
    const _Float16* Ar = xh + (size_t)(r0 + lr) * 512 + lk * 8;
    const _Float16* Br = WtAll + (size_t)(c0 + lr) * 512 + lk * 8;

    f32x4 acc[4];
#pragma unroll
    for (int j = 0; j < 4; ++j) acc[j] = (f32x4){0.f, 0.f, 0.f, 0.f};
    for (int ks = 0; ks < 16; ++ks) {
        f16x8 a = *(const f16x8*)(Ar + ks * 32);
#pragma unroll
        for (int j = 0; j < 4; ++j) {
            f16x8 b = *(const f16x8*)(Br + (size_t)(j * 16) * 512 + ks * 32);
            acc[j] = __builtin_amdgcn_mfma_f32_16x16x32_f16(a, b, acc[j], 0, 0, 0);
        }
    }
    const int m = c0 >> 9;                   // block-uniform: 0=Q 1=K 2=V
    const float* bias = (m == 0) ? bq : (m == 1) ? bk : bv;
#pragma unroll
    for (int j = 0; j < 4; ++j) {
        const int cc = (c0 & 511) + j * 16 + lr;
        const int h = cc >> 6, d = cc & 63;
        const float bb_ = bias[cc];
#pragma unroll
        for (int r = 0; r < 4; ++r) {
            const int row = r0 + lk * 4 + r;
            float val = acc[j][r] + bb_;
            if (m == 0)      Qb[((size_t)h * S + row) * 64 + d] = (_Float16)(val * 0.0625f);
            else if (m == 1) Kb[((size_t)h * S + row) * 64 + d] = (_Float16)val;
            else {
                int bb = row & 31;
                int sp = (row & ~31) | (((bb & 15) << 1) | (bb >> 4));
                Vt[((size_t)h * 64 + d) * S + sp] = (_Float16)val;
            }
        }
    }
}

// -------------------- K2: fused logits + entmax-1.5 + PV --------------------
// Round-12 structure (zw + azw as SEPARATE arrays — the round-13 union forced
// the whole state into scratch). launch_bounds(512,3): ~85-VGPR cap avoids
// round-12's 64-reg spill while allowing 3 blocks/CU. Output AO as fp16
// [S][512] row-major for the MFMA out-projection.
__global__ __launch_bounds__(512, 3) void fused_attn_kernel(
        const _Float16* __restrict__ Qb, const _Float16* __restrict__ Kb,
        const _Float16* __restrict__ Vt, float* __restrict__ attn,
        _Float16* __restrict__ AOh) {
    __shared__ float sred[2][8][16][3];                 // ping-pong stats (3 KB)
    __shared__ __align__(16) f16x2 plds[2][8][16][20];  // padded transpose (20.5 KB)
    __shared__ float pacc[16][64];                      // PV reduction (4 KB)
    const int bid = blockIdx.x;
    const int h = bid & 7, qt = bid >> 3;    // one head per XCD
    const int q0 = qt * 16;
    const int t = threadIdx.x;
    const int w = t >> 6, l = t & 63;
    const int lr = l & 15, lk = l >> 4;
    const int kbase = w * 384;

    ((float*)pacc)[t] = 0.f;
    ((float*)pacc)[t + 512] = 0.f;

    const _Float16* Qh = Qb + ((size_t)h * S) * 64;
    const _Float16* Kh = Kb + ((size_t)h * S) * 64;
    const _Float16* Vh = Vt + (size_t)h * 64 * S;

    const f16x8 aq0 = *(const f16x8*)(Qh + (size_t)(q0 + lr) * 64 + lk * 8);
    const f16x8 aq1 = *(const f16x8*)(Qh + (size_t)(q0 + lr) * 64 + 32 + lk * 8);

    const f16x2 one2  = {(_Float16)1.f, (_Float16)1.f};
    const f16x2 zero2 = {(_Float16)0.f, (_Float16)0.f};
    const f16x2 big2  = {(_Float16)16384.f, (_Float16)16384.f};

    // ---- Pass A: logits once (already w-space); packed stats ----
    f16x2 zw[12][4];
    f16x2 m2[4];
    float s4[4] = {}, q4[4] = {};
#pragma unroll
    for (int r = 0; r < 4; ++r) m2[r] = (f16x2){(_Float16)-60000.f, (_Float16)-60000.f};
#pragma unroll
    for (int jp = 0; jp < 12; ++jp) {
        const _Float16* kp = Kh + (size_t)(kbase + jp * 32 + lr) * 64;
        f16x8 b00 = *(const f16x8*)(kp + lk * 8);
        f16x8 b01 = *(const f16x8*)(kp + 32 + lk * 8);
        f16x8 b10 = *(const f16x8*)(kp + 16 * 64 + lk * 8);
        f16x8 b11 = *(const f16x8*)(kp + 16 * 64 + 32 + lk * 8);
        f32x4 d0 = (f32x4){0.f, 0.f, 0.f, 0.f}, d1 = d0;
        d0 = __builtin_amdgcn_mfma_f32_16x16x32_f16(aq0, b00, d0, 0, 0, 0);
        d0 = __builtin_amdgcn_mfma_f32_16x16x32_f16(aq1, b01, d0, 0, 0, 0);
        d1 = __builtin_amdgcn_mfma_f32_16x16x32_f16(aq0, b10, d1, 0, 0, 0);
        d1 = __builtin_amdgcn_mfma_f32_16x16x32_f16(aq1, b11, d1, 0, 0, 0);
#pragma unroll
        for (int r = 0; r < 4; ++r) {
            f16x2 w2 = cvt_pk(d0[r], d1[r]);
            zw[jp][r] = w2;
            m2[r] = __builtin_elementwise_max(m2[r], w2);
            s4[r] = __builtin_amdgcn_fdot2(w2, one2, s4[r], false);
            q4[r] = __builtin_amdgcn_fdot2(w2, w2, q4[r], false);
        }
    }
    float m4[4];
#pragma unroll
    for (int r = 0; r < 4; ++r) m4[r] = fmaxf((float)m2[r][0], (float)m2[r][1]);
#pragma unroll
    for (int off = 1; off < 16; off <<= 1) {
#pragma unroll
        for (int r = 0; r < 4; ++r) {
            m4[r] = fmaxf(m4[r], __shfl_xor(m4[r], off, 64));
            s4[r] += __shfl_xor(s4[r], off, 64);
            q4[r] += __shfl_xor(q4[r], off, 64);
        }
    }
    if (lr == 0) {
#pragma unroll
        for (int r = 0; r < 4; ++r) {
            sred[0][w][lk * 4 + r][0] = m4[r];
            sred[0][w][lk * 4 + r][1] = s4[r];
            sred[0][w][lk * 4 + r][2] = q4[r];
        }
    }
    __syncthreads();

    // ---- closed-form full-support init (w-space) ----
    const float n = (float)S;
    float Tj;
    {
        float mj = -1e30f, sj = 0.f, qj = 0.f;
#pragma unroll
        for (int ww = 0; ww < 8; ++ww) {
            mj = fmaxf(mj, sred[0][ww][lr][0]);
            sj += sred[0][ww][lr][1];
            qj += sred[0][ww][lr][2];
        }
        float mean = sj * (1.f / n);
        float msq  = qj * (1.f / n);
        float ssv  = n * (msq - mean * mean);
        Tj = mean - sqrtf(fmaxf((1.f - ssv) / n, 0.f));
        Tj = fminf(fmaxf(Tj, mj - 1.0f), mj - 0.01f);
    }
    float T4[4];
#pragma unroll
    for (int r = 0; r < 4; ++r) T4[r] = __shfl(Tj, lk * 4 + r, 64);

    // ---- Pass B: register-only packed Michelot iterations ----
    for (int it = 0; it < 8; ++it) {
        const int buf = (it + 1) & 1;
        f16x2 T2[4];
#pragma unroll
        for (int r = 0; r < 4; ++r) T2[r] = cvt_pk(T4[r], T4[r]);
        float f4[4] = {}, fp4[4] = {}, cn4[4] = {};
#pragma unroll
        for (int jp = 0; jp < 12; ++jp)
#pragma unroll
            for (int r = 0; r < 4; ++r) {
                f16x2 zc = __builtin_elementwise_max(zw[jp][r] - T2[r], zero2);
                f4[r]  = __builtin_amdgcn_fdot2(zc, zc, f4[r], false);
                fp4[r] = __builtin_amdgcn_fdot2(zc, one2, fp4[r], false);
                f16x2 g = __builtin_elementwise_min(zc * big2, one2);
                cn4[r] = __builtin_amdgcn_fdot2(g, one2, cn4[r], false);
            }
#pragma unroll
        for (int off = 1; off < 16; off <<= 1) {
#pragma unroll
            for (int r = 0; r < 4; ++r) {
                f4[r]  += __shfl_xor(f4[r],  off, 64);
                fp4[r] += __shfl_xor(fp4[r], off, 64);
                cn4[r] += __shfl_xor(cn4[r], off, 64);
            }
        }
        if (lr == 0) {
#pragma unroll
            for (int r = 0; r < 4; ++r) {
                sred[buf][w][lk * 4 + r][0] = f4[r];
                sred[buf][w][lk * 4 + r][1] = fp4[r];
                sred[buf][w][lk * 4 + r][2] = cn4[r];
            }
        }
        __syncthreads();
        float fj = 0.f, fpj = 0.f, cnj = 0.f;
#pragma unroll
        for (int ww = 0; ww < 8; ++ww) {
            fj  += sred[buf][ww][lr][0];
            fpj += sred[buf][ww][lr][1];
            cnj += sred[buf][ww][lr][2];
        }
        float ns   = fmaxf(cnj, 1.0f);
        float disc = fmaxf(fpj * fpj - ns * (fj - 1.0f), 0.f);
        float del  = (fpj - sqrtf(disc)) / ns;
#pragma unroll
        for (int r = 0; r < 4; ++r) T4[r] += __shfl(del, lk * 4 + r, 64);
        if (__all(fabsf(del) < 2e-6f)) break;   // block-uniform
    }

    // ---- Phase T: P -> plds -> transposed azw + attn stores ----
    f16x2 T2[4];
#pragma unroll
    for (int r = 0; r < 4; ++r) T2[r] = cvt_pk(T4[r], T4[r]);
    float* arow_t = attn + ((size_t)h * S + q0 + lr) * S + kbase + lk * 4;
    f16x8 azw[12];
#pragma unroll
    for (int jp = 0; jp < 12; ++jp) {
        const int buf = jp & 1;
        union { f16x2 h2[4]; f16x8 v; } pw;
#pragma unroll
        for (int r = 0; r < 4; ++r) {
            f16x2 zc = __builtin_elementwise_max(zw[jp][r] - T2[r], zero2);
            pw.h2[r] = zc * zc;
        }
        *(f16x8*)&plds[buf][w][lr][lk * 4] = pw.v;
        union { f16x2 h2[4]; f16x8 v; } au;
#pragma unroll
        for (int u = 0; u < 4; ++u) au.h2[u] = plds[buf][w][lk * 4 + u][lr];
        azw[jp] = au.v;
        f32x4 lo = {(float)au.v[0], (float)au.v[2], (float)au.v[4], (float)au.v[6]};
        f32x4 hi = {(float)au.v[1], (float)au.v[3], (float)au.v[5], (float)au.v[7]};
        __builtin_nontemporal_store(lo, (f32x4*)(arow_t + jp * 32));
        __builtin_nontemporal_store(hi, (f32x4*)(arow_t + jp * 32 + 16));
    }

    // ---- Phase PV: per dv-quarter, 4-reg acc, imm-offset V loads ----
#pragma unroll
    for (int j = 0; j < 4; ++j) {
        const _Float16* vpj = Vh + (size_t)(j * 16 + lr) * S + kbase + lk * 8;
        f32x4 a4 = (f32x4){0.f, 0.f, 0.f, 0.f};
#pragma unroll
        for (int jp = 0; jp < 12; ++jp) {
            f16x8 b = *(const f16x8*)(vpj + jp * 32);
            a4 = __builtin_amdgcn_mfma_f32_16x16x32_f16(azw[jp], b, a4, 0, 0, 0);
        }
#pragma unroll
        for (int r = 0; r < 4; ++r)
            atomicAdd(&pacc[lk * 4 + r][j * 16 + lr], a4[r]);
    }
    __syncthreads();
    _Float16* AOr = AOh + (size_t)q0 * 512 + h * 64;
#pragma unroll
    for (int u = 0; u < 2; ++u) {
        int idx = t + 512 * u;             // 0..1023
        int row = idx >> 6, col = idx & 63;
        AOr[(size_t)row * 512 + col] = (_Float16)pacc[row][col];
    }
}

// -------------------- K5: out-proj + residual + LayerNorm (MFMA) --------------------
__global__ __launch_bounds__(256) void outproj_mfma_kernel(
        const _Float16* __restrict__ AOh, const _Float16* __restrict__ WtAll,
        const float* __restrict__ bo, const float* __restrict__ x,
        const float* __restrict__ gamma, const float* __restrict__ beta,
        float* __restrict__ out) {
    __shared__ float red[4][16][2];
    const int s0 = blockIdx.x * 16;
    const int t = threadIdx.x, w = t >> 6, l = t & 63;
    const int lr = l & 15, lk = l >> 4;
    const _Float16* Ar = AOh + (size_t)(s0 + lr) * 512 + lk * 8;
    const _Float16* Br = WtAll + (size_t)(1536 + w * 128 + lr) * 512 + lk * 8;

    f32x4 acc[8];
#pragma unroll
    for (int j = 0; j < 8; ++j) acc[j] = (f32x4){0.f, 0.f, 0.f, 0.f};
    for (int ks = 0; ks < 16; ++ks) {
        f16x8 a = *(const f16x8*)(Ar + ks * 32);
#pragma unroll
        for (int j = 0; j < 8; ++j) {
            f16x8 b = *(const f16x8*)(Br + (size_t)(j * 16) * 512 + ks * 32);
            acc[j] = __builtin_amdgcn_mfma_f32_16x16x32_f16(a, b, acc[j], 0, 0, 0);
        }
    }
    float s_[4] = {}, q_[4] = {};
#pragma unroll
    for (int j = 0; j < 8; ++j) {
        const int col = w * 128 + j * 16 + lr;
        const float b0 = bo[col];
#pragma unroll
        for (int r = 0; r < 4; ++r) {
            float y = acc[j][r] + b0 + x[(size_t)(s0 + lk * 4 + r) * 512 + col];
            acc[j][r] = y;
            s_[r] += y;
            q_[r] = fmaf(y, y, q_[r]);
        }
    }
#pragma unroll
    for (int off = 1; off < 16; off <<= 1) {
#pragma unroll
        for (int r = 0; r < 4; ++r) {
            s_[r] += __shfl_xor(s_[r], off, 64);
            q_[r] += __shfl_xor(q_[r], off, 64);
        }
    }
    if (lr == 0) {
#pragma unroll
        for (int r = 0; r < 4; ++r) {
            red[w][lk * 4 + r][0] = s_[r];
            red[w][lk * 4 + r][1] = q_[r];
        }
    }
    __syncthreads();
#pragma unroll
    for (int r = 0; r < 4; ++r) {
        const int rowi = lk * 4 + r;
        float sj = red[0][rowi][0] + red[1][rowi][0] + red[2][rowi][0] + red[3][rowi][0];
        float qj = red[0][rowi][1] + red[1][rowi][1] + red[2][rowi][1] + red[3][rowi][1];
        float mu  = sj * (1.0f / 512.0f);
        float var = qj * (1.0f / 512.0f) - mu * mu;
        float inv = rsqrtf(var + LN_EPS);
        const size_t rbase = (size_t)(s0 + rowi) * 512;
#pragma unroll
        for (int j = 0; j < 8; ++j) {
            const int col = w * 128 + j * 16 + lr;
            out[rbase + col] = (acc[j][r] - mu) * inv * gamma[col] + beta[col];
        }
    }
}

extern "C" void kernel_launch(void* const* d_in, const int* in_sizes, int n_in,
                              void* d_out, int out_size, void* d_ws, size_t ws_size,
                              hipStream_t stream) {
    const float* x     = (const float*)d_in[0];
    const float* Wq    = (const float*)d_in[1];
    const float* bq    = (const float*)d_in[2];
    const float* Wk    = (const float*)d_in[3];
    const float* bk    = (const float*)d_in[4];
    const float* Wv    = (const float*)d_in[5];
    const float* bv    = (const float*)d_in[6];
    const float* Wo    = (const float*)d_in[7];
    const float* bo    = (const float*)d_in[8];
    const float* gamma = (const float*)d_in[9];
    const float* beta  = (const float*)d_in[10];

    float* out  = (float*)d_out;
    float* attn = out + (size_t)S * D;          // tuple output #2

    _Float16* Qb    = (_Float16*)d_ws;          // [H][S][64] fp16, pre-scaled 1/16
    _Float16* Kb    = Qb + (size_t)H * S * 64;  // [H][S][64] fp16
    _Float16* Vt    = Kb + (size_t)H * S * 64;  // [H][64][S] fp16, k-interleaved
    _Float16* xh    = Vt + (size_t)H * S * 64;  // [S][512] fp16
    _Float16* WtAll = xh + (size_t)S * 512;     // [2048][512] fp16 (Q,K,V,O transposed)
    _Float16* AOh   = WtAll + (size_t)2048 * 512; // [S][512] fp16

    prep_w_kernel<<<dim3(2, 8, 4), 256, 0, stream>>>(Wq, Wk, Wv, Wo, WtAll);
    prep_x_kernel<<<dim3(S * D / 2048), 256, 0, stream>>>(x, xh);
    qkv_mfma_kernel<<<dim3(48, 24), 256, 0, stream>>>(xh, WtAll, bq, bk, bv, Qb, Kb, Vt);
    fused_attn_kernel<<<dim3((S / 16) * H), 512, 0, stream>>>(Qb, Kb, Vt, attn, AOh);
    outproj_mfma_kernel<<<dim3(S / 16), 256, 0, stream>>>(AOh, WtAll, bo, x, gamma, beta, out);
}